// Round 3
// baseline (888.228 us; speedup 1.0000x reference)
//
#include <hip/hip_runtime.h>
#include <stdint.h>

#define TMASK ((1u << 19) - 1u)
// Embeddings are uniform in [-1e-4, 1e-4]. Scale by 2^13 before fp16
// rounding so every value is a *normal* fp16; power-of-2 scaling is exact,
// added error <= ~3e-8 absolute. Unscale after the trilinear blend.
#define EMB_SCALE     8192.0f
#define EMB_INV_SCALE (1.0f / 8192.0f)

typedef float    vf2 __attribute__((ext_vector_type(2)));
typedef float    vf4 __attribute__((ext_vector_type(4)));
typedef _Float16 vh2 __attribute__((ext_vector_type(2)));
typedef _Float16 vh4 __attribute__((ext_vector_type(4)));

// grid_size = 2/res, fp32 correctly-rounded (compile-time folded), matching
// the reference's fp32 division. Resolutions: floor(16 * b^l), b = 32^(1/15).
static __device__ const float GS_F[16] = {
    2.0f/16.0f, 2.0f/20.0f, 2.0f/25.0f, 2.0f/32.0f,
    2.0f/40.0f, 2.0f/50.0f, 2.0f/64.0f, 2.0f/80.0f,
    2.0f/101.0f, 2.0f/128.0f, 2.0f/161.0f, 2.0f/203.0f,
    2.0f/256.0f, 2.0f/322.0f, 2.0f/406.0f, 2.0f/512.0f};
// res/2 — exact in fp32.
static __device__ const float INVGS_F[16] = {
    8.0f, 10.0f, 12.5f, 16.0f,
    20.0f, 25.0f, 32.0f, 40.0f,
    50.5f, 64.0f, 80.5f, 101.5f,
    128.0f, 161.0f, 203.0f, 256.0f};

// ---- dense-remap geometry for coarse levels 0-3 (res 16,20,25,32) ----
// Dense table for level l covers (ix,iy,iz) in [0,res]^3 (corners of cells
// 0..res-1; x<1 strictly so ix<=res-1, corner <=res). Entry = fp16-scaled
// emb[hash(ix,iy,iz)] — exact remap, bit-identical hash.
#define N_L0 4913    // 17^3
#define N_L1 9261    // 21^3
#define N_L2 17576   // 26^3
#define N_L3 35937   // 33^3
#define DENSE_OFF1 (N_L0)
#define DENSE_OFF2 (N_L0 + N_L1)
#define DENSE_OFF3 (N_L0 + N_L1 + N_L2)
#define DENSE_TOT  (N_L0 + N_L1 + N_L2 + N_L3)   // 67687 entries = 270.7 KB

static __device__ const int REMAP_S[4]   = {17, 21, 26, 33};
static __device__ const int REMAP_N[4]   = {N_L0, N_L1, N_L2, N_L3};
static __device__ const int REMAP_OFF[4] = {0, DENSE_OFF1, DENSE_OFF2, DENSE_OFF3};

struct Corner8 { vf2 e[8]; float w[8]; };

__device__ __forceinline__ vf2 load_entry(const vf2* __restrict__ tb, uint32_t h) {
    return tb[h];
}
__device__ __forceinline__ vf2 load_entry(const vh2* __restrict__ tb, uint32_t h) {
    const vh2 v = tb[h];            // one 4 B dword gather
    vf2 r; r.x = (float)v.x; r.y = (float)v.y;
    return r;
}

template <typename T>
__device__ __forceinline__ void gather_level(
    const T* __restrict__ tb, float cx, float cy, float cz,
    float gs, float ivg, Corner8& g)
{
    const float ux = (cx + 1.0f) * ivg;
    const float uy = (cy + 1.0f) * ivg;
    const float uz = (cz + 1.0f) * ivg;
    const float fx = floorf(ux), fy = floorf(uy), fz = floorf(uz);
    const int ix = (int)fx, iy = (int)fy, iz = (int)fz;
    const float wx = (cx - (fx * gs - 1.0f)) * ivg;
    const float wy = (cy - (fy * gs - 1.0f)) * ivg;
    const float wz = (cz - (fz * gs - 1.0f)) * ivg;

    const uint32_t px0 = (uint32_t)ix * 73856093u, px1 = px0 + 73856093u;
    const uint32_t py0 = (uint32_t)iy * 19349663u, py1 = py0 + 19349663u;
    const uint32_t pz0 = (uint32_t)iz * 83492791u, pz1 = pz0 + 83492791u;

    g.e[0] = load_entry(tb, (px0 ^ py0 ^ pz0) & TMASK);
    g.e[1] = load_entry(tb, (px0 ^ py0 ^ pz1) & TMASK);
    g.e[2] = load_entry(tb, (px0 ^ py1 ^ pz0) & TMASK);
    g.e[3] = load_entry(tb, (px0 ^ py1 ^ pz1) & TMASK);
    g.e[4] = load_entry(tb, (px1 ^ py0 ^ pz0) & TMASK);
    g.e[5] = load_entry(tb, (px1 ^ py0 ^ pz1) & TMASK);
    g.e[6] = load_entry(tb, (px1 ^ py1 ^ pz0) & TMASK);
    g.e[7] = load_entry(tb, (px1 ^ py1 ^ pz1) & TMASK);

    const float wxm = 1.0f - wx, wym = 1.0f - wy, wzm = 1.0f - wz;
    const float c00 = wxm * wym, c01 = wxm * wy;
    const float c10 = wx  * wym, c11 = wx  * wy;
    g.w[0] = c00 * wzm; g.w[1] = c00 * wz;
    g.w[2] = c01 * wzm; g.w[3] = c01 * wz;
    g.w[4] = c10 * wzm; g.w[5] = c10 * wz;
    g.w[6] = c11 * wzm; g.w[7] = c11 * wz;
}

__device__ __forceinline__ vf2 blend(const Corner8& g) {
    vf2 r;
    r.x = g.w[0]*g.e[0].x + g.w[1]*g.e[1].x + g.w[2]*g.e[2].x + g.w[3]*g.e[3].x
        + g.w[4]*g.e[4].x + g.w[5]*g.e[5].x + g.w[6]*g.e[6].x + g.w[7]*g.e[7].x;
    r.y = g.w[0]*g.e[0].y + g.w[1]*g.e[1].y + g.w[2]*g.e[2].y + g.w[3]*g.e[3].y
        + g.w[4]*g.e[4].y + g.w[5]*g.e[5].y + g.w[6]*g.e[6].y + g.w[7]*g.e[7].y;
    return r;
}

// fp32 [L][T][2] -> scaled fp16 [L][T][2]. Read 16 B (2 entries), write 8 B.
__global__ __launch_bounds__(256) void convert_kernel(
    const vf4* __restrict__ emb, vh4* __restrict__ tb, int n4)
{
    const int i = blockIdx.x * blockDim.x + threadIdx.x;
    if (i >= n4) return;
    const vf4 v = __builtin_nontemporal_load(emb + i);
    vh4 o;
    o.x = (_Float16)(v.x * EMB_SCALE);
    o.y = (_Float16)(v.y * EMB_SCALE);
    o.z = (_Float16)(v.z * EMB_SCALE);
    o.w = (_Float16)(v.w * EMB_SCALE);
    tb[i] = o;   // plain store: table should live in L2/L3
}

// Build dense fp16 tables for levels 0-3: dense[l][(jx*S+jy)*S+jz] =
// fp16(emb[l][hash(jx,jy,jz)] * SCALE). 67687 scattered gathers — trivial.
__global__ __launch_bounds__(256) void remap_kernel(
    const vf2* __restrict__ emb, vh2* __restrict__ dense)
{
    const int l = blockIdx.y;
    const int S = REMAP_S[l];
    const int n = REMAP_N[l];
    const int d = blockIdx.x * 256 + threadIdx.x;
    if (d >= n) return;
    const int jz = d % S;
    const int r  = d / S;
    const int jy = r % S;
    const int jx = r / S;
    const uint32_t h = ((uint32_t)jx * 73856093u
                      ^ (uint32_t)jy * 19349663u
                      ^ (uint32_t)jz * 83492791u) & TMASK;
    const vf2 e = emb[((size_t)l << 19) + h];
    vh2 o; o.x = (_Float16)(e.x * EMB_SCALE); o.y = (_Float16)(e.y * EMB_SCALE);
    dense[REMAP_OFF[l] + d] = o;
}

__device__ __forceinline__ vf2 unpack_u32(uint32_t r) {
    const vh2 v = __builtin_bit_cast(vh2, r);
    vf2 o; o.x = (float)v.x; o.y = (float)v.y;
    return o;
}

// One coarse level served from an LDS-resident dense table. The DS pipe
// bypasses the TA/L2 divergent-gather throughput cap (~3.6 cyc/lane) that
// pins the global-gather kernels; random banks average 2-way = free.
template <int RES>
__device__ __forceinline__ vf2 coarse_point(
    const uint32_t* __restrict__ tb, float cx, float cy, float cz)
{
    constexpr int S = RES + 1, S2 = S * S;
    constexpr float gs  = 2.0f / (float)RES;     // == GS_F[l], exact
    constexpr float ivg = (float)RES * 0.5f;     // == INVGS_F[l], exact

    const float ux = (cx + 1.0f) * ivg;
    const float uy = (cy + 1.0f) * ivg;
    const float uz = (cz + 1.0f) * ivg;
    const float fx = floorf(ux), fy = floorf(uy), fz = floorf(uz);
    const int ix = (int)fx, iy = (int)fy, iz = (int)fz;
    const float wx = (cx - (fx * gs - 1.0f)) * ivg;
    const float wy = (cy - (fy * gs - 1.0f)) * ivg;
    const float wz = (cz - (fz * gs - 1.0f)) * ivg;
    const int d0 = (ix * S + iy) * S + iz;

    const vf2 e0 = unpack_u32(tb[d0]);
    const vf2 e1 = unpack_u32(tb[d0 + 1]);
    const vf2 e2 = unpack_u32(tb[d0 + S]);
    const vf2 e3 = unpack_u32(tb[d0 + S + 1]);
    const vf2 e4 = unpack_u32(tb[d0 + S2]);
    const vf2 e5 = unpack_u32(tb[d0 + S2 + 1]);
    const vf2 e6 = unpack_u32(tb[d0 + S2 + S]);
    const vf2 e7 = unpack_u32(tb[d0 + S2 + S + 1]);

    const float wxm = 1.0f - wx, wym = 1.0f - wy, wzm = 1.0f - wz;
    const float c00 = wxm * wym, c01 = wxm * wy;
    const float c10 = wx  * wym, c11 = wx  * wy;
    const float w0 = c00 * wzm, w1 = c00 * wz, w2 = c01 * wzm, w3 = c01 * wz;
    const float w4 = c10 * wzm, w5 = c10 * wz, w6 = c11 * wzm, w7 = c11 * wz;

    vf2 r;
    r.x = w0*e0.x + w1*e1.x + w2*e2.x + w3*e3.x
        + w4*e4.x + w5*e5.x + w6*e6.x + w7*e7.x;
    r.y = w0*e0.y + w1*e1.y + w2*e2.y + w3*e3.y
        + w4*e4.y + w5*e5.y + w6*e6.y + w7*e7.y;
    r.x *= EMB_INV_SCALE; r.y *= EMB_INV_SCALE;
    return r;
}

// Levels 0+1 (56.7 KB LDS), grid-stride over points.
__global__ __launch_bounds__(1024) void coarse01_kernel(
    const float* __restrict__ x, const uint32_t* __restrict__ dense,
    vf2* __restrict__ ws, int B)
{
    extern __shared__ uint32_t lds[];
    constexpr int NTOT = N_L0 + N_L1;
    for (int i = threadIdx.x; i < NTOT; i += 1024) lds[i] = dense[i];
    __syncthreads();

    const int stride = gridDim.x * 1024;
    for (int p = blockIdx.x * 1024 + threadIdx.x; p < B; p += stride) {
        const float cx = fminf(fmaxf(__builtin_nontemporal_load(x + 3*p + 0), -1.0f), 1.0f);
        const float cy = fminf(fmaxf(__builtin_nontemporal_load(x + 3*p + 1), -1.0f), 1.0f);
        const float cz = fminf(fmaxf(__builtin_nontemporal_load(x + 3*p + 2), -1.0f), 1.0f);
        const vf2 r0 = coarse_point<16>(lds, cx, cy, cz);
        const vf2 r1 = coarse_point<20>(lds + N_L0, cx, cy, cz);
        __builtin_nontemporal_store(r0, &ws[p]);
        __builtin_nontemporal_store(r1, &ws[(long)B + p]);
    }
}

// Level 2 (70.3 KB LDS).
__global__ __launch_bounds__(1024) void coarse2_kernel(
    const float* __restrict__ x, const uint32_t* __restrict__ dense,
    vf2* __restrict__ ws, int B)
{
    extern __shared__ uint32_t lds[];
    for (int i = threadIdx.x; i < N_L2; i += 1024) lds[i] = dense[i];
    __syncthreads();

    const int stride = gridDim.x * 1024;
    for (int p = blockIdx.x * 1024 + threadIdx.x; p < B; p += stride) {
        const float cx = fminf(fmaxf(__builtin_nontemporal_load(x + 3*p + 0), -1.0f), 1.0f);
        const float cy = fminf(fmaxf(__builtin_nontemporal_load(x + 3*p + 1), -1.0f), 1.0f);
        const float cz = fminf(fmaxf(__builtin_nontemporal_load(x + 3*p + 2), -1.0f), 1.0f);
        const vf2 r2 = coarse_point<25>(lds, cx, cy, cz);
        __builtin_nontemporal_store(r2, &ws[(long)2 * B + p]);
    }
}

// Level 3 (143.7 KB LDS, 1 block/CU).
__global__ __launch_bounds__(1024) void coarse3_kernel(
    const float* __restrict__ x, const uint32_t* __restrict__ dense,
    vf2* __restrict__ ws, int B)
{
    extern __shared__ uint32_t lds[];
    for (int i = threadIdx.x; i < N_L3; i += 1024) lds[i] = dense[i];
    __syncthreads();

    const int stride = gridDim.x * 1024;
    for (int p = blockIdx.x * 1024 + threadIdx.x; p < B; p += stride) {
        const float cx = fminf(fmaxf(__builtin_nontemporal_load(x + 3*p + 0), -1.0f), 1.0f);
        const float cy = fminf(fmaxf(__builtin_nontemporal_load(x + 3*p + 1), -1.0f), 1.0f);
        const float cz = fminf(fmaxf(__builtin_nontemporal_load(x + 3*p + 2), -1.0f), 1.0f);
        const vf2 r3 = coarse_point<32>(lds, cx, cy, cz);
        __builtin_nontemporal_store(r3, &ws[(long)3 * B + p]);
    }
}

// Levels 4-15 fused, 2 points per thread (split-half, lane-coalesced), fp16
// tables. One launch: results stored per level so registers die per level
// (low VGPR), compiler interleaves levels' gathers for deep MLP.
template <int L0, int L1>
__global__ __launch_bounds__(256) void fine_kernel(
    const float* __restrict__ x,
    const vh2* __restrict__ tbl,
    vf2* __restrict__ ws,
    int B, int half)
{
    const int p0 = blockIdx.x * blockDim.x + threadIdx.x;
    if (p0 >= half) return;
    const int p1 = p0 + half;
    const bool has1 = p1 < B;
    const int p1c = has1 ? p1 : p0;

    const float ax = __builtin_nontemporal_load(x + 3*p0 + 0);
    const float ay = __builtin_nontemporal_load(x + 3*p0 + 1);
    const float az = __builtin_nontemporal_load(x + 3*p0 + 2);
    const float bx = __builtin_nontemporal_load(x + 3*p1c + 0);
    const float by = __builtin_nontemporal_load(x + 3*p1c + 1);
    const float bz = __builtin_nontemporal_load(x + 3*p1c + 2);

    const float cax = fminf(fmaxf(ax, -1.0f), 1.0f);
    const float cay = fminf(fmaxf(ay, -1.0f), 1.0f);
    const float caz = fminf(fmaxf(az, -1.0f), 1.0f);
    const float cbx = fminf(fmaxf(bx, -1.0f), 1.0f);
    const float cby = fminf(fmaxf(by, -1.0f), 1.0f);
    const float cbz = fminf(fmaxf(bz, -1.0f), 1.0f);

#pragma unroll
    for (int l = L0; l <= L1; ++l) {
        const float gs  = GS_F[l];
        const float ivg = INVGS_F[l];
        const vh2* __restrict__ tb = tbl + ((size_t)l << 19);

        Corner8 ga, gb;
        gather_level(tb, cax, cay, caz, gs, ivg, ga);
        gather_level(tb, cbx, cby, cbz, gs, ivg, gb);

        vf2 ra = blend(ga);
        vf2 rb = blend(gb);
        ra.x *= EMB_INV_SCALE; ra.y *= EMB_INV_SCALE;
        rb.x *= EMB_INV_SCALE; rb.y *= EMB_INV_SCALE;

        __builtin_nontemporal_store(ra, &ws[(long)l * B + p0]);
        if (has1) __builtin_nontemporal_store(rb, &ws[(long)l * B + p1]);
    }
}

// ws [16][B] float2 -> out [B][8] float4, LDS-tiled so global writes are
// lane-consecutive float4s (full 64B lines per wave store).
__global__ __launch_bounds__(256) void transpose_kernel(
    const vf2* __restrict__ ws, vf4* __restrict__ out, int B)
{
    __shared__ vf2 tile[16][257];   // +1 pad: store-phase reads <=2-way
    const int t = threadIdx.x;
    const int base = blockIdx.x * 256;

#pragma unroll
    for (int l = 0; l < 16; ++l) {
        const int b = base + t;
        if (b < B) tile[l][t] = __builtin_nontemporal_load(&ws[(long)l * B + b]);
    }
    __syncthreads();

#pragma unroll
    for (int k = 0; k < 8; ++k) {
        const int flat = k * 256 + t;        // float4 index within block's 2048
        const int p = flat >> 3;             // local point
        const int j = flat & 7;              // float4 slot within point
        if (base + p < B) {
            const vf2 a = tile[2*j][p];
            const vf2 c = tile[2*j+1][p];
            vf4 v; v.x = a.x; v.y = a.y; v.z = c.x; v.w = c.y;
            __builtin_nontemporal_store(v, &out[(long)base * 8 + flat]);
        }
    }
}

// Fallback (workspace too small): R2 fp32 monolith, needs no workspace.
template <typename T, bool SCALED>
__global__ __launch_bounds__(256) void monolith_kernel(
    const float* __restrict__ x,
    const T* __restrict__ tbl,
    vf4* __restrict__ out,
    int B, int half)
{
    const int t = threadIdx.x;
    const int base = blockIdx.x * 256;
    const int p0r = base + t;
    const int p0 = p0r < half ? p0r : half - 1;
    const int p1r = p0 + half;
    const int p1 = p1r < B ? p1r : B - 1;

    const float ax = __builtin_nontemporal_load(x + 3*p0 + 0);
    const float ay = __builtin_nontemporal_load(x + 3*p0 + 1);
    const float az = __builtin_nontemporal_load(x + 3*p0 + 2);
    const float bx = __builtin_nontemporal_load(x + 3*p1 + 0);
    const float by = __builtin_nontemporal_load(x + 3*p1 + 1);
    const float bz = __builtin_nontemporal_load(x + 3*p1 + 2);

    const float cax = fminf(fmaxf(ax, -1.0f), 1.0f);
    const float cay = fminf(fmaxf(ay, -1.0f), 1.0f);
    const float caz = fminf(fmaxf(az, -1.0f), 1.0f);
    const float cbx = fminf(fmaxf(bx, -1.0f), 1.0f);
    const float cby = fminf(fmaxf(by, -1.0f), 1.0f);
    const float cbz = fminf(fmaxf(bz, -1.0f), 1.0f);

    vf2 oa[16], ob[16];
#pragma unroll
    for (int l = 0; l < 16; ++l) {
        const float gs  = GS_F[l];
        const float ivg = INVGS_F[l];
        const T* __restrict__ tb = tbl + ((size_t)l << 19);
        Corner8 ga, gb;
        gather_level(tb, cax, cay, caz, gs, ivg, ga);
        gather_level(tb, cbx, cby, cbz, gs, ivg, gb);
        vf2 ra = blend(ga);
        vf2 rb = blend(gb);
        if constexpr (SCALED) {
            ra.x *= EMB_INV_SCALE; ra.y *= EMB_INV_SCALE;
            rb.x *= EMB_INV_SCALE; rb.y *= EMB_INV_SCALE;
        }
        oa[l] = ra; ob[l] = rb;
    }

    __shared__ vf2 tile[16][257];
#pragma unroll
    for (int l = 0; l < 16; ++l) tile[l][t] = oa[l];
    __syncthreads();
#pragma unroll
    for (int k = 0; k < 8; ++k) {
        const int flat = k * 256 + t;
        const int p = flat >> 3;
        const int j = flat & 7;
        if (base + p < half) {
            const vf2 a = tile[2*j][p];
            const vf2 c = tile[2*j+1][p];
            vf4 v; v.x = a.x; v.y = a.y; v.z = c.x; v.w = c.y;
            __builtin_nontemporal_store(v, &out[(long)(base + p) * 8 + j]);
        }
    }
    __syncthreads();
#pragma unroll
    for (int l = 0; l < 16; ++l) tile[l][t] = ob[l];
    __syncthreads();
#pragma unroll
    for (int k = 0; k < 8; ++k) {
        const int flat = k * 256 + t;
        const int p = flat >> 3;
        const int j = flat & 7;
        const long pt = (long)base + half + p;
        if (pt < B) {
            const vf2 a = tile[2*j][p];
            const vf2 c = tile[2*j+1][p];
            vf4 v; v.x = a.x; v.y = a.y; v.z = c.x; v.w = c.y;
            __builtin_nontemporal_store(v, &out[pt * 8 + j]);
        }
    }
}

extern "C" void kernel_launch(void* const* d_in, const int* in_sizes, int n_in,
                              void* d_out, int out_size, void* d_ws, size_t ws_size,
                              hipStream_t stream) {
    const float* x   = (const float*)d_in[0];
    const float* emb = (const float*)d_in[1];
    const int B = in_sizes[0] / 3;

    const int half = (B + 1) / 2;
    const int grid = (half + 255) / 256;
    const size_t tbl_bytes = (size_t)16 * 524288 * sizeof(vh2);   // 32 MB fp16
    const size_t ws_bytes  = (size_t)B * 16 * sizeof(vf2);        // 128 MB @ B=1M
    const size_t dense_bytes = (size_t)DENSE_TOT * sizeof(vh2);   // 270.7 KB

    if (ws_size >= tbl_bytes + ws_bytes && (size_t)out_size >= dense_bytes) {
        vh2* tb = (vh2*)d_ws;
        vf2* ws = (vf2*)((char*)d_ws + tbl_bytes);
        vh2* dense = (vh2*)d_out;   // dead storage until transpose overwrites

        // Allow >64 KB dynamic LDS (no-op if unsupported; errors ignored).
        static int attr_done = 0;
        if (!attr_done) {
            (void)hipFuncSetAttribute((const void*)coarse01_kernel,
                hipFuncAttributeMaxDynamicSharedMemorySize, (N_L0 + N_L1) * 4);
            (void)hipFuncSetAttribute((const void*)coarse2_kernel,
                hipFuncAttributeMaxDynamicSharedMemorySize, N_L2 * 4);
            (void)hipFuncSetAttribute((const void*)coarse3_kernel,
                hipFuncAttributeMaxDynamicSharedMemorySize, N_L3 * 4);
            attr_done = 1;
        }

        // 1) dense remap tables for levels 0-3 (into d_out scratch)
        remap_kernel<<<dim3((N_L3 + 255) / 256, 4), 256, 0, stream>>>(
            (const vf2*)emb, dense);
        // 2) coarse levels from LDS (DS pipe — off the gather-cap path)
        coarse01_kernel<<<512, 1024, (N_L0 + N_L1) * 4, stream>>>(
            x, (const uint32_t*)dense, ws, B);
        coarse2_kernel<<<512, 1024, N_L2 * 4, stream>>>(
            x, (const uint32_t*)dense + DENSE_OFF2, ws, B);
        coarse3_kernel<<<256, 1024, N_L3 * 4, stream>>>(
            x, (const uint32_t*)dense + DENSE_OFF3, ws, B);
        // 3) fp16 tables right before fine so they're L2/L3-warm
        const int n4 = 16 * 524288 * 2 / 4;
        convert_kernel<<<(n4 + 255) / 256, 256, 0, stream>>>(
            (const vf4*)emb, (vh4*)tb, n4);
        // 4) fine levels 4-15, one fused launch
        fine_kernel<4, 15><<<grid, 256, 0, stream>>>(x, tb, ws, B, half);
        // 5) transpose to output layout
        transpose_kernel<<<(B + 255) / 256, 256, 0, stream>>>(ws, (vf4*)d_out, B);
    } else {
        // Fallback: fp32 monolith, zero workspace.
        monolith_kernel<vf2, false><<<grid, 256, 0, stream>>>(
            x, (const vf2*)emb, (vf4*)d_out, B, half);
    }
}

// Round 4
// 660.733 us; speedup vs baseline: 1.3443x; 1.3443x over previous
//
#include <hip/hip_runtime.h>
#include <stdint.h>

#define TMASK ((1u << 19) - 1u)
// Embeddings are uniform in [-1e-4, 1e-4]. Scale by 2^13 before fp16
// rounding so every value is a *normal* fp16; power-of-2 scaling is exact,
// added error <= ~3e-8 absolute. Unscale after the trilinear blend.
#define EMB_SCALE     8192.0f
#define EMB_INV_SCALE (1.0f / 8192.0f)

typedef float    vf2 __attribute__((ext_vector_type(2)));
typedef float    vf4 __attribute__((ext_vector_type(4)));
typedef _Float16 vh2 __attribute__((ext_vector_type(2)));
typedef _Float16 vh4 __attribute__((ext_vector_type(4)));

// grid_size = 2/res, fp32 correctly-rounded (compile-time folded), matching
// the reference's fp32 division. Resolutions: floor(16 * b^l), b = 32^(1/15).
static __device__ const float GS_F[16] = {
    2.0f/16.0f, 2.0f/20.0f, 2.0f/25.0f, 2.0f/32.0f,
    2.0f/40.0f, 2.0f/50.0f, 2.0f/64.0f, 2.0f/80.0f,
    2.0f/101.0f, 2.0f/128.0f, 2.0f/161.0f, 2.0f/203.0f,
    2.0f/256.0f, 2.0f/322.0f, 2.0f/406.0f, 2.0f/512.0f};
// res/2 — exact in fp32.
static __device__ const float INVGS_F[16] = {
    8.0f, 10.0f, 12.5f, 16.0f,
    20.0f, 25.0f, 32.0f, 40.0f,
    50.5f, 64.0f, 80.5f, 101.5f,
    128.0f, 161.0f, 203.0f, 256.0f};

// ---- dense-remap geometry for coarse levels 0-3 (res 16,20,25,32) ----
#define N_L0 4913    // 17^3
#define N_L1 9261    // 21^3
#define N_L2 17576   // 26^3
#define N_L3 35937   // 33^3
#define DENSE_OFF1 (N_L0)
#define DENSE_OFF2 (N_L0 + N_L1)
#define DENSE_OFF3 (N_L0 + N_L1 + N_L2)
#define DENSE_TOT  (N_L0 + N_L1 + N_L2 + N_L3)   // 67687 entries = 270.7 KB

static __device__ const int REMAP_S[4]   = {17, 21, 26, 33};
static __device__ const int REMAP_N[4]   = {N_L0, N_L1, N_L2, N_L3};
static __device__ const int REMAP_OFF[4] = {0, DENSE_OFF1, DENSE_OFF2, DENSE_OFF3};

struct Corner8 { vf2 e[8]; float w[8]; };

__device__ __forceinline__ vf2 load_entry(const vf2* __restrict__ tb, uint32_t h) {
    return tb[h];
}
__device__ __forceinline__ vf2 load_entry(const vh2* __restrict__ tb, uint32_t h) {
    const vh2 v = tb[h];            // one 4 B dword gather
    vf2 r; r.x = (float)v.x; r.y = (float)v.y;
    return r;
}

template <typename T>
__device__ __forceinline__ void gather_level(
    const T* __restrict__ tb, float cx, float cy, float cz,
    float gs, float ivg, Corner8& g)
{
    const float ux = (cx + 1.0f) * ivg;
    const float uy = (cy + 1.0f) * ivg;
    const float uz = (cz + 1.0f) * ivg;
    const float fx = floorf(ux), fy = floorf(uy), fz = floorf(uz);
    const int ix = (int)fx, iy = (int)fy, iz = (int)fz;
    const float wx = (cx - (fx * gs - 1.0f)) * ivg;
    const float wy = (cy - (fy * gs - 1.0f)) * ivg;
    const float wz = (cz - (fz * gs - 1.0f)) * ivg;

    const uint32_t px0 = (uint32_t)ix * 73856093u, px1 = px0 + 73856093u;
    const uint32_t py0 = (uint32_t)iy * 19349663u, py1 = py0 + 19349663u;
    const uint32_t pz0 = (uint32_t)iz * 83492791u, pz1 = pz0 + 83492791u;

    g.e[0] = load_entry(tb, (px0 ^ py0 ^ pz0) & TMASK);
    g.e[1] = load_entry(tb, (px0 ^ py0 ^ pz1) & TMASK);
    g.e[2] = load_entry(tb, (px0 ^ py1 ^ pz0) & TMASK);
    g.e[3] = load_entry(tb, (px0 ^ py1 ^ pz1) & TMASK);
    g.e[4] = load_entry(tb, (px1 ^ py0 ^ pz0) & TMASK);
    g.e[5] = load_entry(tb, (px1 ^ py0 ^ pz1) & TMASK);
    g.e[6] = load_entry(tb, (px1 ^ py1 ^ pz0) & TMASK);
    g.e[7] = load_entry(tb, (px1 ^ py1 ^ pz1) & TMASK);

    const float wxm = 1.0f - wx, wym = 1.0f - wy, wzm = 1.0f - wz;
    const float c00 = wxm * wym, c01 = wxm * wy;
    const float c10 = wx  * wym, c11 = wx  * wy;
    g.w[0] = c00 * wzm; g.w[1] = c00 * wz;
    g.w[2] = c01 * wzm; g.w[3] = c01 * wz;
    g.w[4] = c10 * wzm; g.w[5] = c10 * wz;
    g.w[6] = c11 * wzm; g.w[7] = c11 * wz;
}

__device__ __forceinline__ vf2 blend(const Corner8& g) {
    vf2 r;
    r.x = g.w[0]*g.e[0].x + g.w[1]*g.e[1].x + g.w[2]*g.e[2].x + g.w[3]*g.e[3].x
        + g.w[4]*g.e[4].x + g.w[5]*g.e[5].x + g.w[6]*g.e[6].x + g.w[7]*g.e[7].x;
    r.y = g.w[0]*g.e[0].y + g.w[1]*g.e[1].y + g.w[2]*g.e[2].y + g.w[3]*g.e[3].y
        + g.w[4]*g.e[4].y + g.w[5]*g.e[5].y + g.w[6]*g.e[6].y + g.w[7]*g.e[7].y;
    return r;
}

// fp32 [L][T][2] -> scaled fp16 [L][T][2]. Read 16 B (2 entries), write 8 B.
__global__ __launch_bounds__(256) void convert_kernel(
    const vf4* __restrict__ emb, vh4* __restrict__ tb, int n4)
{
    const int i = blockIdx.x * blockDim.x + threadIdx.x;
    if (i >= n4) return;
    const vf4 v = __builtin_nontemporal_load(emb + i);
    vh4 o;
    o.x = (_Float16)(v.x * EMB_SCALE);
    o.y = (_Float16)(v.y * EMB_SCALE);
    o.z = (_Float16)(v.z * EMB_SCALE);
    o.w = (_Float16)(v.w * EMB_SCALE);
    tb[i] = o;
}

// Build dense fp16 tables for levels 0-3 (exact hash remap, 67687 gathers).
__global__ __launch_bounds__(256) void remap_kernel(
    const vf2* __restrict__ emb, vh2* __restrict__ dense)
{
    const int l = blockIdx.y;
    const int S = REMAP_S[l];
    const int n = REMAP_N[l];
    const int d = blockIdx.x * 256 + threadIdx.x;
    if (d >= n) return;
    const int jz = d % S;
    const int r  = d / S;
    const int jy = r % S;
    const int jx = r / S;
    const uint32_t h = ((uint32_t)jx * 73856093u
                      ^ (uint32_t)jy * 19349663u
                      ^ (uint32_t)jz * 83492791u) & TMASK;
    const vf2 e = emb[((size_t)l << 19) + h];
    vh2 o; o.x = (_Float16)(e.x * EMB_SCALE); o.y = (_Float16)(e.y * EMB_SCALE);
    dense[REMAP_OFF[l] + d] = o;
}

__device__ __forceinline__ vf2 unpack_u32(uint32_t r) {
    const vh2 v = __builtin_bit_cast(vh2, r);
    vf2 o; o.x = (float)v.x; o.y = (float)v.y;
    return o;
}

// One coarse level served from an LDS-resident dense table (DS pipe —
// overlaps with the global gather latency, nearly free).
template <int RES>
__device__ __forceinline__ vf2 coarse_point(
    const uint32_t* __restrict__ tb, float cx, float cy, float cz)
{
    constexpr int S = RES + 1, S2 = S * S;
    constexpr float gs  = 2.0f / (float)RES;
    constexpr float ivg = (float)RES * 0.5f;

    const float ux = (cx + 1.0f) * ivg;
    const float uy = (cy + 1.0f) * ivg;
    const float uz = (cz + 1.0f) * ivg;
    const float fx = floorf(ux), fy = floorf(uy), fz = floorf(uz);
    const int ix = (int)fx, iy = (int)fy, iz = (int)fz;
    const float wx = (cx - (fx * gs - 1.0f)) * ivg;
    const float wy = (cy - (fy * gs - 1.0f)) * ivg;
    const float wz = (cz - (fz * gs - 1.0f)) * ivg;
    const int d0 = (ix * S + iy) * S + iz;

    const vf2 e0 = unpack_u32(tb[d0]);
    const vf2 e1 = unpack_u32(tb[d0 + 1]);
    const vf2 e2 = unpack_u32(tb[d0 + S]);
    const vf2 e3 = unpack_u32(tb[d0 + S + 1]);
    const vf2 e4 = unpack_u32(tb[d0 + S2]);
    const vf2 e5 = unpack_u32(tb[d0 + S2 + 1]);
    const vf2 e6 = unpack_u32(tb[d0 + S2 + S]);
    const vf2 e7 = unpack_u32(tb[d0 + S2 + S + 1]);

    const float wxm = 1.0f - wx, wym = 1.0f - wy, wzm = 1.0f - wz;
    const float c00 = wxm * wym, c01 = wxm * wy;
    const float c10 = wx  * wym, c11 = wx  * wy;
    const float w0 = c00 * wzm, w1 = c00 * wz, w2 = c01 * wzm, w3 = c01 * wz;
    const float w4 = c10 * wzm, w5 = c10 * wz, w6 = c11 * wzm, w7 = c11 * wz;

    vf2 r;
    r.x = w0*e0.x + w1*e1.x + w2*e2.x + w3*e3.x
        + w4*e4.x + w5*e5.x + w6*e6.x + w7*e7.x;
    r.y = w0*e0.y + w1*e1.y + w2*e2.y + w3*e3.y
        + w4*e4.y + w5*e5.y + w6*e6.y + w7*e7.y;
    r.x *= EMB_INV_SCALE; r.y *= EMB_INV_SCALE;
    return r;
}

// Pair kernel: levels {LA, LB} via global fp16 gathers (4 MB combined table
// = one XCD L2 -> request-bound, not HBM-bound), 2 points per thread
// (split-half, lane-coalesced). CMODE folds LDS-coarse levels in:
//   CMODE 0: none          (NT=256, no dynamic LDS)
//   CMODE 1: levels 0+1    (NT=1024, 56.7 KB)
//   CMODE 2: level 2       (NT=1024, 70.3 KB)
//   CMODE 3: level 3       (NT=1024, 143.7 KB)
// The coarse DS-pipe work hides under the global-gather latency; gather
// rate is occupancy-insensitive (R2: full rate at 11% occupancy).
template <int LA, int LB, int CMODE, int NT>
__global__ __launch_bounds__(NT) void pair_kernel(
    const float* __restrict__ x,
    const vh2* __restrict__ tbl,
    const uint32_t* __restrict__ dense,
    vf2* __restrict__ ws,
    int B, int half)
{
    extern __shared__ uint32_t lds[];
    if constexpr (CMODE == 1) {
        for (int i = threadIdx.x; i < N_L0 + N_L1; i += NT) lds[i] = dense[i];
        __syncthreads();
    } else if constexpr (CMODE == 2) {
        for (int i = threadIdx.x; i < N_L2; i += NT) lds[i] = dense[DENSE_OFF2 + i];
        __syncthreads();
    } else if constexpr (CMODE == 3) {
        for (int i = threadIdx.x; i < N_L3; i += NT) lds[i] = dense[DENSE_OFF3 + i];
        __syncthreads();
    }

    const int p0 = blockIdx.x * NT + threadIdx.x;
    if (p0 >= half) return;
    const int p1 = p0 + half;
    const bool has1 = p1 < B;
    const int p1c = has1 ? p1 : p0;

    const float ax = __builtin_nontemporal_load(x + 3*p0 + 0);
    const float ay = __builtin_nontemporal_load(x + 3*p0 + 1);
    const float az = __builtin_nontemporal_load(x + 3*p0 + 2);
    const float bx = __builtin_nontemporal_load(x + 3*p1c + 0);
    const float by = __builtin_nontemporal_load(x + 3*p1c + 1);
    const float bz = __builtin_nontemporal_load(x + 3*p1c + 2);

    const float cax = fminf(fmaxf(ax, -1.0f), 1.0f);
    const float cay = fminf(fmaxf(ay, -1.0f), 1.0f);
    const float caz = fminf(fmaxf(az, -1.0f), 1.0f);
    const float cbx = fminf(fmaxf(bx, -1.0f), 1.0f);
    const float cby = fminf(fmaxf(by, -1.0f), 1.0f);
    const float cbz = fminf(fmaxf(bz, -1.0f), 1.0f);

    // Fine gathers: issue both levels x both points (32 lane-requests).
    const vh2* __restrict__ tbA = tbl + ((size_t)LA << 19);
    const vh2* __restrict__ tbB = tbl + ((size_t)LB << 19);
    Corner8 gaA, gbA, gaB, gbB;
    gather_level(tbA, cax, cay, caz, GS_F[LA], INVGS_F[LA], gaA);
    gather_level(tbA, cbx, cby, cbz, GS_F[LA], INVGS_F[LA], gbA);
    gather_level(tbB, cax, cay, caz, GS_F[LB], INVGS_F[LB], gaB);
    gather_level(tbB, cbx, cby, cbz, GS_F[LB], INVGS_F[LB], gbB);

    // Coarse LDS work while the global gathers are in flight.
    if constexpr (CMODE == 1) {
        const vf2 a0 = coarse_point<16>(lds, cax, cay, caz);
        const vf2 b0 = coarse_point<16>(lds, cbx, cby, cbz);
        const vf2 a1 = coarse_point<20>(lds + N_L0, cax, cay, caz);
        const vf2 b1 = coarse_point<20>(lds + N_L0, cbx, cby, cbz);
        __builtin_nontemporal_store(a0, &ws[p0]);
        if (has1) __builtin_nontemporal_store(b0, &ws[p1]);
        __builtin_nontemporal_store(a1, &ws[(long)B + p0]);
        if (has1) __builtin_nontemporal_store(b1, &ws[(long)B + p1]);
    } else if constexpr (CMODE == 2) {
        const vf2 a2 = coarse_point<25>(lds, cax, cay, caz);
        const vf2 b2 = coarse_point<25>(lds, cbx, cby, cbz);
        __builtin_nontemporal_store(a2, &ws[(long)2 * B + p0]);
        if (has1) __builtin_nontemporal_store(b2, &ws[(long)2 * B + p1]);
    } else if constexpr (CMODE == 3) {
        const vf2 a3 = coarse_point<32>(lds, cax, cay, caz);
        const vf2 b3 = coarse_point<32>(lds, cbx, cby, cbz);
        __builtin_nontemporal_store(a3, &ws[(long)3 * B + p0]);
        if (has1) __builtin_nontemporal_store(b3, &ws[(long)3 * B + p1]);
    }

    vf2 raA = blend(gaA), rbA = blend(gbA);
    vf2 raB = blend(gaB), rbB = blend(gbB);
    raA.x *= EMB_INV_SCALE; raA.y *= EMB_INV_SCALE;
    rbA.x *= EMB_INV_SCALE; rbA.y *= EMB_INV_SCALE;
    raB.x *= EMB_INV_SCALE; raB.y *= EMB_INV_SCALE;
    rbB.x *= EMB_INV_SCALE; rbB.y *= EMB_INV_SCALE;

    __builtin_nontemporal_store(raA, &ws[(long)LA * B + p0]);
    if (has1) __builtin_nontemporal_store(rbA, &ws[(long)LA * B + p1]);
    __builtin_nontemporal_store(raB, &ws[(long)LB * B + p0]);
    if (has1) __builtin_nontemporal_store(rbB, &ws[(long)LB * B + p1]);
}

// ws [16][B] float2 -> out [B][8] float4, LDS-tiled so global writes are
// lane-consecutive float4s (full 64B lines per wave store).
__global__ __launch_bounds__(256) void transpose_kernel(
    const vf2* __restrict__ ws, vf4* __restrict__ out, int B)
{
    __shared__ vf2 tile[16][257];   // +1 pad: store-phase reads <=2-way
    const int t = threadIdx.x;
    const int base = blockIdx.x * 256;

#pragma unroll
    for (int l = 0; l < 16; ++l) {
        const int b = base + t;
        if (b < B) tile[l][t] = __builtin_nontemporal_load(&ws[(long)l * B + b]);
    }
    __syncthreads();

#pragma unroll
    for (int k = 0; k < 8; ++k) {
        const int flat = k * 256 + t;
        const int p = flat >> 3;
        const int j = flat & 7;
        if (base + p < B) {
            const vf2 a = tile[2*j][p];
            const vf2 c = tile[2*j+1][p];
            vf4 v; v.x = a.x; v.y = a.y; v.z = c.x; v.w = c.y;
            __builtin_nontemporal_store(v, &out[(long)base * 8 + flat]);
        }
    }
}

// Fallback (workspace too small): fp32 monolith, needs no workspace.
__global__ __launch_bounds__(256) void monolith_kernel(
    const float* __restrict__ x,
    const vf2* __restrict__ tbl,
    vf4* __restrict__ out,
    int B, int half)
{
    const int t = threadIdx.x;
    const int base = blockIdx.x * 256;
    const int p0r = base + t;
    const int p0 = p0r < half ? p0r : half - 1;
    const int p1r = p0 + half;
    const int p1 = p1r < B ? p1r : B - 1;

    const float cax = fminf(fmaxf(__builtin_nontemporal_load(x + 3*p0 + 0), -1.0f), 1.0f);
    const float cay = fminf(fmaxf(__builtin_nontemporal_load(x + 3*p0 + 1), -1.0f), 1.0f);
    const float caz = fminf(fmaxf(__builtin_nontemporal_load(x + 3*p0 + 2), -1.0f), 1.0f);
    const float cbx = fminf(fmaxf(__builtin_nontemporal_load(x + 3*p1 + 0), -1.0f), 1.0f);
    const float cby = fminf(fmaxf(__builtin_nontemporal_load(x + 3*p1 + 1), -1.0f), 1.0f);
    const float cbz = fminf(fmaxf(__builtin_nontemporal_load(x + 3*p1 + 2), -1.0f), 1.0f);

    vf2 oa[16], ob[16];
#pragma unroll
    for (int l = 0; l < 16; ++l) {
        const vf2* __restrict__ tb = tbl + ((size_t)l << 19);
        Corner8 ga, gb;
        gather_level(tb, cax, cay, caz, GS_F[l], INVGS_F[l], ga);
        gather_level(tb, cbx, cby, cbz, GS_F[l], INVGS_F[l], gb);
        oa[l] = blend(ga); ob[l] = blend(gb);
    }

    __shared__ vf2 tile[16][257];
#pragma unroll
    for (int l = 0; l < 16; ++l) tile[l][t] = oa[l];
    __syncthreads();
#pragma unroll
    for (int k = 0; k < 8; ++k) {
        const int flat = k * 256 + t;
        const int p = flat >> 3;
        const int j = flat & 7;
        if (base + p < half) {
            const vf2 a = tile[2*j][p];
            const vf2 c = tile[2*j+1][p];
            vf4 v; v.x = a.x; v.y = a.y; v.z = c.x; v.w = c.y;
            __builtin_nontemporal_store(v, &out[(long)(base + p) * 8 + j]);
        }
    }
    __syncthreads();
#pragma unroll
    for (int l = 0; l < 16; ++l) tile[l][t] = ob[l];
    __syncthreads();
#pragma unroll
    for (int k = 0; k < 8; ++k) {
        const int flat = k * 256 + t;
        const int p = flat >> 3;
        const int j = flat & 7;
        const long pt = (long)base + half + p;
        if (pt < B) {
            const vf2 a = tile[2*j][p];
            const vf2 c = tile[2*j+1][p];
            vf4 v; v.x = a.x; v.y = a.y; v.z = c.x; v.w = c.y;
            __builtin_nontemporal_store(v, &out[pt * 8 + j]);
        }
    }
}

extern "C" void kernel_launch(void* const* d_in, const int* in_sizes, int n_in,
                              void* d_out, int out_size, void* d_ws, size_t ws_size,
                              hipStream_t stream) {
    const float* x   = (const float*)d_in[0];
    const float* emb = (const float*)d_in[1];
    const int B = in_sizes[0] / 3;

    const int half = (B + 1) / 2;
    const size_t tbl_bytes = (size_t)16 * 524288 * sizeof(vh2);   // 32 MB fp16
    const size_t ws_bytes  = (size_t)B * 16 * sizeof(vf2);        // 128 MB @ B=1M
    const size_t dense_bytes = (size_t)DENSE_TOT * sizeof(vh2);   // 270.7 KB

    if (ws_size >= tbl_bytes + ws_bytes && (size_t)out_size >= dense_bytes) {
        vh2* tb = (vh2*)d_ws;
        vf2* ws = (vf2*)((char*)d_ws + tbl_bytes);
        vh2* dense = (vh2*)d_out;   // dead storage until transpose overwrites
        const uint32_t* dn = (const uint32_t*)dense;

        static int attr_done = 0;
        if (!attr_done) {
            (void)hipFuncSetAttribute(
                reinterpret_cast<const void*>(&pair_kernel<4, 5, 1, 1024>),
                hipFuncAttributeMaxDynamicSharedMemorySize, (N_L0 + N_L1) * 4);
            (void)hipFuncSetAttribute(
                reinterpret_cast<const void*>(&pair_kernel<6, 7, 2, 1024>),
                hipFuncAttributeMaxDynamicSharedMemorySize, N_L2 * 4);
            (void)hipFuncSetAttribute(
                reinterpret_cast<const void*>(&pair_kernel<8, 9, 3, 1024>),
                hipFuncAttributeMaxDynamicSharedMemorySize, N_L3 * 4);
            attr_done = 1;
        }

        const int n4 = 16 * 524288 * 2 / 4;
        convert_kernel<<<(n4 + 255) / 256, 256, 0, stream>>>(
            (const vf4*)emb, (vh4*)tb, n4);
        remap_kernel<<<dim3((N_L3 + 255) / 256, 4), 256, 0, stream>>>(
            (const vf2*)emb, dense);

        const int g1024 = (half + 1023) / 1024;
        const int g256  = (half + 255) / 256;
        pair_kernel<4, 5, 1, 1024><<<g1024, 1024, (N_L0 + N_L1) * 4, stream>>>(
            x, tb, dn, ws, B, half);
        pair_kernel<6, 7, 2, 1024><<<g1024, 1024, N_L2 * 4, stream>>>(
            x, tb, dn, ws, B, half);
        pair_kernel<8, 9, 3, 1024><<<g1024, 1024, N_L3 * 4, stream>>>(
            x, tb, dn, ws, B, half);
        pair_kernel<10, 11, 0, 256><<<g256, 256, 0, stream>>>(
            x, tb, dn, ws, B, half);
        pair_kernel<12, 13, 0, 256><<<g256, 256, 0, stream>>>(
            x, tb, dn, ws, B, half);
        pair_kernel<14, 15, 0, 256><<<g256, 256, 0, stream>>>(
            x, tb, dn, ws, B, half);

        transpose_kernel<<<(B + 255) / 256, 256, 0, stream>>>(ws, (vf4*)d_out, B);
    } else {
        const int grid = (half + 255) / 256;
        monolith_kernel<<<grid, 256, 0, stream>>>(
            x, (const vf2*)emb, (vf4*)d_out, B, half);
    }
}

// Round 5
// 654.087 us; speedup vs baseline: 1.3580x; 1.0102x over previous
//
#include <hip/hip_runtime.h>
#include <stdint.h>

#define TMASK ((1u << 19) - 1u)
// Embeddings are uniform in [-1e-4, 1e-4]. Scale by 2^13 before fp16
// rounding so every value is a *normal* fp16; power-of-2 scaling is exact,
// added error <= ~3e-8 absolute. Unscale after the trilinear blend.
#define EMB_SCALE     8192.0f
#define EMB_INV_SCALE (1.0f / 8192.0f)

typedef float    vf2 __attribute__((ext_vector_type(2)));
typedef float    vf4 __attribute__((ext_vector_type(4)));
typedef _Float16 vh2 __attribute__((ext_vector_type(2)));
typedef _Float16 vh4 __attribute__((ext_vector_type(4)));
typedef int      i32x4 __attribute__((ext_vector_type(4)));

// grid_size = 2/res, fp32 correctly-rounded (compile-time folded), matching
// the reference's fp32 division. Resolutions: floor(16 * b^l), b = 32^(1/15).
static __device__ const float GS_F[16] = {
    2.0f/16.0f, 2.0f/20.0f, 2.0f/25.0f, 2.0f/32.0f,
    2.0f/40.0f, 2.0f/50.0f, 2.0f/64.0f, 2.0f/80.0f,
    2.0f/101.0f, 2.0f/128.0f, 2.0f/161.0f, 2.0f/203.0f,
    2.0f/256.0f, 2.0f/322.0f, 2.0f/406.0f, 2.0f/512.0f};
// res/2 — exact in fp32.
static __device__ const float INVGS_F[16] = {
    8.0f, 10.0f, 12.5f, 16.0f,
    20.0f, 25.0f, 32.0f, 40.0f,
    50.5f, 64.0f, 80.5f, 101.5f,
    128.0f, 161.0f, 203.0f, 256.0f};

// ---- dense-remap geometry for coarse levels 0-3 (res 16,20,25,32) ----
#define N_L0 4913    // 17^3
#define N_L1 9261    // 21^3
#define N_L2 17576   // 26^3
#define N_L3 35937   // 33^3
#define DENSE_OFF1 (N_L0)
#define DENSE_OFF2 (N_L0 + N_L1)
#define DENSE_OFF3 (N_L0 + N_L1 + N_L2)
#define DENSE_TOT  (N_L0 + N_L1 + N_L2 + N_L3)   // 67687 entries = 270.7 KB

static __device__ const int REMAP_S[4]   = {17, 21, 26, 33};
static __device__ const int REMAP_N[4]   = {N_L0, N_L1, N_L2, N_L3};
static __device__ const int REMAP_OFF[4] = {0, DENSE_OFF1, DENSE_OFF2, DENSE_OFF3};

struct Corner8 { vf2 e[8]; float w[8]; };
struct HW8 { uint32_t h[8]; float w[8]; };

__device__ __forceinline__ vf2 load_entry(const vf2* __restrict__ tb, uint32_t h) {
    return tb[h];
}

// fp32 gather path (fallback monolith only).
template <typename T>
__device__ __forceinline__ void gather_level(
    const T* __restrict__ tb, float cx, float cy, float cz,
    float gs, float ivg, Corner8& g)
{
    const float ux = (cx + 1.0f) * ivg;
    const float uy = (cy + 1.0f) * ivg;
    const float uz = (cz + 1.0f) * ivg;
    const float fx = floorf(ux), fy = floorf(uy), fz = floorf(uz);
    const int ix = (int)fx, iy = (int)fy, iz = (int)fz;
    const float wx = (cx - (fx * gs - 1.0f)) * ivg;
    const float wy = (cy - (fy * gs - 1.0f)) * ivg;
    const float wz = (cz - (fz * gs - 1.0f)) * ivg;

    const uint32_t px0 = (uint32_t)ix * 73856093u, px1 = px0 + 73856093u;
    const uint32_t py0 = (uint32_t)iy * 19349663u, py1 = py0 + 19349663u;
    const uint32_t pz0 = (uint32_t)iz * 83492791u, pz1 = pz0 + 83492791u;

    g.e[0] = load_entry(tb, (px0 ^ py0 ^ pz0) & TMASK);
    g.e[1] = load_entry(tb, (px0 ^ py0 ^ pz1) & TMASK);
    g.e[2] = load_entry(tb, (px0 ^ py1 ^ pz0) & TMASK);
    g.e[3] = load_entry(tb, (px0 ^ py1 ^ pz1) & TMASK);
    g.e[4] = load_entry(tb, (px1 ^ py0 ^ pz0) & TMASK);
    g.e[5] = load_entry(tb, (px1 ^ py0 ^ pz1) & TMASK);
    g.e[6] = load_entry(tb, (px1 ^ py1 ^ pz0) & TMASK);
    g.e[7] = load_entry(tb, (px1 ^ py1 ^ pz1) & TMASK);

    const float wxm = 1.0f - wx, wym = 1.0f - wy, wzm = 1.0f - wz;
    const float c00 = wxm * wym, c01 = wxm * wy;
    const float c10 = wx  * wym, c11 = wx  * wy;
    g.w[0] = c00 * wzm; g.w[1] = c00 * wz;
    g.w[2] = c01 * wzm; g.w[3] = c01 * wz;
    g.w[4] = c10 * wzm; g.w[5] = c10 * wz;
    g.w[6] = c11 * wzm; g.w[7] = c11 * wz;
}

__device__ __forceinline__ vf2 blend(const Corner8& g) {
    vf2 r;
    r.x = g.w[0]*g.e[0].x + g.w[1]*g.e[1].x + g.w[2]*g.e[2].x + g.w[3]*g.e[3].x
        + g.w[4]*g.e[4].x + g.w[5]*g.e[5].x + g.w[6]*g.e[6].x + g.w[7]*g.e[7].x;
    r.y = g.w[0]*g.e[0].y + g.w[1]*g.e[1].y + g.w[2]*g.e[2].y + g.w[3]*g.e[3].y
        + g.w[4]*g.e[4].y + g.w[5]*g.e[5].y + g.w[6]*g.e[6].y + g.w[7]*g.e[7].y;
    return r;
}

// Hash + trilinear weights only (no loads) — feeds the batched sc0 issue.
template <int L>
__device__ __forceinline__ void hash_weights(
    float cx, float cy, float cz, HW8& o)
{
    const float gs  = GS_F[L];
    const float ivg = INVGS_F[L];
    const float ux = (cx + 1.0f) * ivg;
    const float uy = (cy + 1.0f) * ivg;
    const float uz = (cz + 1.0f) * ivg;
    const float fx = floorf(ux), fy = floorf(uy), fz = floorf(uz);
    const int ix = (int)fx, iy = (int)fy, iz = (int)fz;
    const float wx = (cx - (fx * gs - 1.0f)) * ivg;
    const float wy = (cy - (fy * gs - 1.0f)) * ivg;
    const float wz = (cz - (fz * gs - 1.0f)) * ivg;

    const uint32_t px0 = (uint32_t)ix * 73856093u, px1 = px0 + 73856093u;
    const uint32_t py0 = (uint32_t)iy * 19349663u, py1 = py0 + 19349663u;
    const uint32_t pz0 = (uint32_t)iz * 83492791u, pz1 = pz0 + 83492791u;
    o.h[0] = (px0 ^ py0 ^ pz0) & TMASK;
    o.h[1] = (px0 ^ py0 ^ pz1) & TMASK;
    o.h[2] = (px0 ^ py1 ^ pz0) & TMASK;
    o.h[3] = (px0 ^ py1 ^ pz1) & TMASK;
    o.h[4] = (px1 ^ py0 ^ pz0) & TMASK;
    o.h[5] = (px1 ^ py0 ^ pz1) & TMASK;
    o.h[6] = (px1 ^ py1 ^ pz0) & TMASK;
    o.h[7] = (px1 ^ py1 ^ pz1) & TMASK;

    const float wxm = 1.0f - wx, wym = 1.0f - wy, wzm = 1.0f - wz;
    const float c00 = wxm * wym, c01 = wxm * wy;
    const float c10 = wx  * wym, c11 = wx  * wy;
    o.w[0] = c00 * wzm; o.w[1] = c00 * wz;
    o.w[2] = c01 * wzm; o.w[3] = c01 * wz;
    o.w[4] = c10 * wzm; o.w[5] = c10 * wz;
    o.w[6] = c11 * wzm; o.w[7] = c11 * wz;
}

__device__ __forceinline__ i32x4 make_srsrc(const void* p, uint32_t bytes) {
    union { const void* p; uint32_t w[2]; } a; a.p = p;
    i32x4 r;
    r.x = (int)a.w[0];
    r.y = (int)a.w[1];          // stride=0
    r.z = (int)bytes;           // num_records (bytes, stride==0)
    r.w = 0x00020000;           // raw dword descriptor
    return r;
}

// Batched sc0 gather: buffer_load_dword with device-coherence (sc0) bypasses
// the 32 KB vL1 — no 64 B line fill per random dword, request served from L2.
// EXPERIMENT R5: tests whether the ~0.28 req/cyc/CU gather cap is the
// L1-fill bus (sc0 helps) or the L2-side random-request limit (no change).
template <int L>
__device__ __forceinline__ void issue8_sc0(i32x4 srsrc, const HW8& hw, uint32_t* r) {
#pragma unroll
    for (int k = 0; k < 8; ++k) {
        const uint32_t voff = ((uint32_t)L << 21) + hw.h[k] * 4u;
        asm volatile("buffer_load_dword %0, %1, %2, 0 offen sc0"
                     : "=v"(r[k])
                     : "v"(voff), "s"(srsrc));
    }
}

__device__ __forceinline__ void wait_vm0() {
    asm volatile("s_waitcnt vmcnt(0)" ::: "memory");
    __builtin_amdgcn_sched_barrier(0);   // rule #18: fence VALU consumers
}

__device__ __forceinline__ vf2 unpack_u32(uint32_t r) {
    const vh2 v = __builtin_bit_cast(vh2, r);
    vf2 o; o.x = (float)v.x; o.y = (float)v.y;
    return o;
}

__device__ __forceinline__ vf2 blend8u(const uint32_t* r, const float* w) {
    vf2 a; a.x = 0.0f; a.y = 0.0f;
#pragma unroll
    for (int k = 0; k < 8; ++k) {
        const vf2 e = unpack_u32(r[k]);
        a.x += w[k] * e.x;
        a.y += w[k] * e.y;
    }
    a.x *= EMB_INV_SCALE; a.y *= EMB_INV_SCALE;
    return a;
}

// fp32 [L][T][2] -> scaled fp16 [L][T][2]. Read 16 B (2 entries), write 8 B.
__global__ __launch_bounds__(256) void convert_kernel(
    const vf4* __restrict__ emb, vh4* __restrict__ tb, int n4)
{
    const int i = blockIdx.x * blockDim.x + threadIdx.x;
    if (i >= n4) return;
    const vf4 v = __builtin_nontemporal_load(emb + i);
    vh4 o;
    o.x = (_Float16)(v.x * EMB_SCALE);
    o.y = (_Float16)(v.y * EMB_SCALE);
    o.z = (_Float16)(v.z * EMB_SCALE);
    o.w = (_Float16)(v.w * EMB_SCALE);
    tb[i] = o;
}

// Build dense fp16 tables for levels 0-3 (exact hash remap, 67687 gathers).
__global__ __launch_bounds__(256) void remap_kernel(
    const vf2* __restrict__ emb, vh2* __restrict__ dense)
{
    const int l = blockIdx.y;
    const int S = REMAP_S[l];
    const int n = REMAP_N[l];
    const int d = blockIdx.x * 256 + threadIdx.x;
    if (d >= n) return;
    const int jz = d % S;
    const int r  = d / S;
    const int jy = r % S;
    const int jx = r / S;
    const uint32_t h = ((uint32_t)jx * 73856093u
                      ^ (uint32_t)jy * 19349663u
                      ^ (uint32_t)jz * 83492791u) & TMASK;
    const vf2 e = emb[((size_t)l << 19) + h];
    vh2 o; o.x = (_Float16)(e.x * EMB_SCALE); o.y = (_Float16)(e.y * EMB_SCALE);
    dense[REMAP_OFF[l] + d] = o;
}

// One coarse level served from an LDS-resident dense table (DS pipe —
// overlaps with the in-flight global gathers, nearly free).
template <int RES>
__device__ __forceinline__ vf2 coarse_point(
    const uint32_t* __restrict__ tb, float cx, float cy, float cz)
{
    constexpr int S = RES + 1, S2 = S * S;
    constexpr float gs  = 2.0f / (float)RES;
    constexpr float ivg = (float)RES * 0.5f;

    const float ux = (cx + 1.0f) * ivg;
    const float uy = (cy + 1.0f) * ivg;
    const float uz = (cz + 1.0f) * ivg;
    const float fx = floorf(ux), fy = floorf(uy), fz = floorf(uz);
    const int ix = (int)fx, iy = (int)fy, iz = (int)fz;
    const float wx = (cx - (fx * gs - 1.0f)) * ivg;
    const float wy = (cy - (fy * gs - 1.0f)) * ivg;
    const float wz = (cz - (fz * gs - 1.0f)) * ivg;
    const int d0 = (ix * S + iy) * S + iz;

    const vf2 e0 = unpack_u32(tb[d0]);
    const vf2 e1 = unpack_u32(tb[d0 + 1]);
    const vf2 e2 = unpack_u32(tb[d0 + S]);
    const vf2 e3 = unpack_u32(tb[d0 + S + 1]);
    const vf2 e4 = unpack_u32(tb[d0 + S2]);
    const vf2 e5 = unpack_u32(tb[d0 + S2 + 1]);
    const vf2 e6 = unpack_u32(tb[d0 + S2 + S]);
    const vf2 e7 = unpack_u32(tb[d0 + S2 + S + 1]);

    const float wxm = 1.0f - wx, wym = 1.0f - wy, wzm = 1.0f - wz;
    const float c00 = wxm * wym, c01 = wxm * wy;
    const float c10 = wx  * wym, c11 = wx  * wy;
    const float w0 = c00 * wzm, w1 = c00 * wz, w2 = c01 * wzm, w3 = c01 * wz;
    const float w4 = c10 * wzm, w5 = c10 * wz, w6 = c11 * wzm, w7 = c11 * wz;

    vf2 r;
    r.x = w0*e0.x + w1*e1.x + w2*e2.x + w3*e3.x
        + w4*e4.x + w5*e5.x + w6*e6.x + w7*e7.x;
    r.y = w0*e0.y + w1*e1.y + w2*e2.y + w3*e3.y
        + w4*e4.y + w5*e5.y + w6*e6.y + w7*e7.y;
    r.x *= EMB_INV_SCALE; r.y *= EMB_INV_SCALE;
    return r;
}

// Pair kernel: levels {LA, LB} via batched sc0 gathers (4 MB combined table
// = one XCD L2), 2 points per thread (split-half, lane-coalesced). CMODE
// folds LDS-coarse levels in (work placed in the gather shadow):
//   CMODE 0: none          (NT=256)
//   CMODE 1: levels 0+1    (NT=1024, 56.7 KB)
//   CMODE 2: level 2       (NT=1024, 70.3 KB)
//   CMODE 3: level 3       (NT=1024, 143.7 KB)
template <int LA, int LB, int CMODE, int NT>
__global__ __launch_bounds__(NT) void pair_kernel(
    const float* __restrict__ x,
    const vh2* __restrict__ tbl,
    const uint32_t* __restrict__ dense,
    vf2* __restrict__ ws,
    int B, int half)
{
    extern __shared__ uint32_t lds[];
    if constexpr (CMODE == 1) {
        for (int i = threadIdx.x; i < N_L0 + N_L1; i += NT) lds[i] = dense[i];
        __syncthreads();
    } else if constexpr (CMODE == 2) {
        for (int i = threadIdx.x; i < N_L2; i += NT) lds[i] = dense[DENSE_OFF2 + i];
        __syncthreads();
    } else if constexpr (CMODE == 3) {
        for (int i = threadIdx.x; i < N_L3; i += NT) lds[i] = dense[DENSE_OFF3 + i];
        __syncthreads();
    }

    const int p0 = blockIdx.x * NT + threadIdx.x;
    if (p0 >= half) return;
    const int p1 = p0 + half;
    const bool has1 = p1 < B;
    const int p1c = has1 ? p1 : p0;

    const float ax = __builtin_nontemporal_load(x + 3*p0 + 0);
    const float ay = __builtin_nontemporal_load(x + 3*p0 + 1);
    const float az = __builtin_nontemporal_load(x + 3*p0 + 2);
    const float bx = __builtin_nontemporal_load(x + 3*p1c + 0);
    const float by = __builtin_nontemporal_load(x + 3*p1c + 1);
    const float bz = __builtin_nontemporal_load(x + 3*p1c + 2);

    const float cax = fminf(fmaxf(ax, -1.0f), 1.0f);
    const float cay = fminf(fmaxf(ay, -1.0f), 1.0f);
    const float caz = fminf(fmaxf(az, -1.0f), 1.0f);
    const float cbx = fminf(fmaxf(bx, -1.0f), 1.0f);
    const float cby = fminf(fmaxf(by, -1.0f), 1.0f);
    const float cbz = fminf(fmaxf(bz, -1.0f), 1.0f);

    // Hashes + weights for both levels x both points, then batch-issue all
    // 32 sc0 gathers so they overlap each other and the coarse LDS work.
    HW8 wAa, wAb, wBa, wBb;
    hash_weights<LA>(cax, cay, caz, wAa);
    hash_weights<LA>(cbx, cby, cbz, wAb);
    hash_weights<LB>(cax, cay, caz, wBa);
    hash_weights<LB>(cbx, cby, cbz, wBb);

    const i32x4 srsrc = make_srsrc(tbl, 16u * 524288u * 4u);   // 32 MB
    uint32_t rAa[8], rAb[8], rBa[8], rBb[8];
    issue8_sc0<LA>(srsrc, wAa, rAa);
    issue8_sc0<LA>(srsrc, wAb, rAb);
    issue8_sc0<LB>(srsrc, wBa, rBa);
    issue8_sc0<LB>(srsrc, wBb, rBb);

    // Coarse LDS work while the gathers are in flight (stores deferred so
    // vmcnt(0) doesn't wait on our own writes).
    vf2 c0a, c0b, c1a, c1b;
    if constexpr (CMODE == 1) {
        c0a = coarse_point<16>(lds, cax, cay, caz);
        c0b = coarse_point<16>(lds, cbx, cby, cbz);
        c1a = coarse_point<20>(lds + N_L0, cax, cay, caz);
        c1b = coarse_point<20>(lds + N_L0, cbx, cby, cbz);
    } else if constexpr (CMODE == 2) {
        c0a = coarse_point<25>(lds, cax, cay, caz);
        c0b = coarse_point<25>(lds, cbx, cby, cbz);
    } else if constexpr (CMODE == 3) {
        c0a = coarse_point<32>(lds, cax, cay, caz);
        c0b = coarse_point<32>(lds, cbx, cby, cbz);
    }

    wait_vm0();

    const vf2 raA = blend8u(rAa, wAa.w);
    const vf2 rbA = blend8u(rAb, wAb.w);
    const vf2 raB = blend8u(rBa, wBa.w);
    const vf2 rbB = blend8u(rBb, wBb.w);

    __builtin_nontemporal_store(raA, &ws[(long)LA * B + p0]);
    if (has1) __builtin_nontemporal_store(rbA, &ws[(long)LA * B + p1]);
    __builtin_nontemporal_store(raB, &ws[(long)LB * B + p0]);
    if (has1) __builtin_nontemporal_store(rbB, &ws[(long)LB * B + p1]);

    if constexpr (CMODE == 1) {
        __builtin_nontemporal_store(c0a, &ws[p0]);
        if (has1) __builtin_nontemporal_store(c0b, &ws[p1]);
        __builtin_nontemporal_store(c1a, &ws[(long)B + p0]);
        if (has1) __builtin_nontemporal_store(c1b, &ws[(long)B + p1]);
    } else if constexpr (CMODE == 2) {
        __builtin_nontemporal_store(c0a, &ws[(long)2 * B + p0]);
        if (has1) __builtin_nontemporal_store(c0b, &ws[(long)2 * B + p1]);
    } else if constexpr (CMODE == 3) {
        __builtin_nontemporal_store(c0a, &ws[(long)3 * B + p0]);
        if (has1) __builtin_nontemporal_store(c0b, &ws[(long)3 * B + p1]);
    }
}

// ws [16][B] float2 -> out [B][8] float4, LDS-tiled so global writes are
// lane-consecutive float4s (full 64B lines per wave store).
__global__ __launch_bounds__(256) void transpose_kernel(
    const vf2* __restrict__ ws, vf4* __restrict__ out, int B)
{
    __shared__ vf2 tile[16][257];   // +1 pad: store-phase reads <=2-way
    const int t = threadIdx.x;
    const int base = blockIdx.x * 256;

#pragma unroll
    for (int l = 0; l < 16; ++l) {
        const int b = base + t;
        if (b < B) tile[l][t] = __builtin_nontemporal_load(&ws[(long)l * B + b]);
    }
    __syncthreads();

#pragma unroll
    for (int k = 0; k < 8; ++k) {
        const int flat = k * 256 + t;
        const int p = flat >> 3;
        const int j = flat & 7;
        if (base + p < B) {
            const vf2 a = tile[2*j][p];
            const vf2 c = tile[2*j+1][p];
            vf4 v; v.x = a.x; v.y = a.y; v.z = c.x; v.w = c.y;
            __builtin_nontemporal_store(v, &out[(long)base * 8 + flat]);
        }
    }
}

// Fallback (workspace too small): fp32 monolith, needs no workspace.
__global__ __launch_bounds__(256) void monolith_kernel(
    const float* __restrict__ x,
    const vf2* __restrict__ tbl,
    vf4* __restrict__ out,
    int B, int half)
{
    const int t = threadIdx.x;
    const int base = blockIdx.x * 256;
    const int p0r = base + t;
    const int p0 = p0r < half ? p0r : half - 1;
    const int p1r = p0 + half;
    const int p1 = p1r < B ? p1r : B - 1;

    const float cax = fminf(fmaxf(__builtin_nontemporal_load(x + 3*p0 + 0), -1.0f), 1.0f);
    const float cay = fminf(fmaxf(__builtin_nontemporal_load(x + 3*p0 + 1), -1.0f), 1.0f);
    const float caz = fminf(fmaxf(__builtin_nontemporal_load(x + 3*p0 + 2), -1.0f), 1.0f);
    const float cbx = fminf(fmaxf(__builtin_nontemporal_load(x + 3*p1 + 0), -1.0f), 1.0f);
    const float cby = fminf(fmaxf(__builtin_nontemporal_load(x + 3*p1 + 1), -1.0f), 1.0f);
    const float cbz = fminf(fmaxf(__builtin_nontemporal_load(x + 3*p1 + 2), -1.0f), 1.0f);

    vf2 oa[16], ob[16];
#pragma unroll
    for (int l = 0; l < 16; ++l) {
        const vf2* __restrict__ tb = tbl + ((size_t)l << 19);
        Corner8 ga, gb;
        gather_level(tb, cax, cay, caz, GS_F[l], INVGS_F[l], ga);
        gather_level(tb, cbx, cby, cbz, GS_F[l], INVGS_F[l], gb);
        oa[l] = blend(ga); ob[l] = blend(gb);
    }

    __shared__ vf2 tile[16][257];
#pragma unroll
    for (int l = 0; l < 16; ++l) tile[l][t] = oa[l];
    __syncthreads();
#pragma unroll
    for (int k = 0; k < 8; ++k) {
        const int flat = k * 256 + t;
        const int p = flat >> 3;
        const int j = flat & 7;
        if (base + p < half) {
            const vf2 a = tile[2*j][p];
            const vf2 c = tile[2*j+1][p];
            vf4 v; v.x = a.x; v.y = a.y; v.z = c.x; v.w = c.y;
            __builtin_nontemporal_store(v, &out[(long)(base + p) * 8 + j]);
        }
    }
    __syncthreads();
#pragma unroll
    for (int l = 0; l < 16; ++l) tile[l][t] = ob[l];
    __syncthreads();
#pragma unroll
    for (int k = 0; k < 8; ++k) {
        const int flat = k * 256 + t;
        const int p = flat >> 3;
        const int j = flat & 7;
        const long pt = (long)base + half + p;
        if (pt < B) {
            const vf2 a = tile[2*j][p];
            const vf2 c = tile[2*j+1][p];
            vf4 v; v.x = a.x; v.y = a.y; v.z = c.x; v.w = c.y;
            __builtin_nontemporal_store(v, &out[pt * 8 + j]);
        }
    }
}

extern "C" void kernel_launch(void* const* d_in, const int* in_sizes, int n_in,
                              void* d_out, int out_size, void* d_ws, size_t ws_size,
                              hipStream_t stream) {
    const float* x   = (const float*)d_in[0];
    const float* emb = (const float*)d_in[1];
    const int B = in_sizes[0] / 3;

    const int half = (B + 1) / 2;
    const size_t tbl_bytes = (size_t)16 * 524288 * sizeof(vh2);   // 32 MB fp16
    const size_t ws_bytes  = (size_t)B * 16 * sizeof(vf2);        // 128 MB @ B=1M
    const size_t dense_bytes = (size_t)DENSE_TOT * sizeof(vh2);   // 270.7 KB

    if (ws_size >= tbl_bytes + ws_bytes && (size_t)out_size >= dense_bytes) {
        vh2* tb = (vh2*)d_ws;
        vf2* ws = (vf2*)((char*)d_ws + tbl_bytes);
        vh2* dense = (vh2*)d_out;   // dead storage until transpose overwrites
        const uint32_t* dn = (const uint32_t*)dense;

        static int attr_done = 0;
        if (!attr_done) {
            (void)hipFuncSetAttribute(
                reinterpret_cast<const void*>(&pair_kernel<4, 5, 1, 1024>),
                hipFuncAttributeMaxDynamicSharedMemorySize, (N_L0 + N_L1) * 4);
            (void)hipFuncSetAttribute(
                reinterpret_cast<const void*>(&pair_kernel<6, 7, 2, 1024>),
                hipFuncAttributeMaxDynamicSharedMemorySize, N_L2 * 4);
            (void)hipFuncSetAttribute(
                reinterpret_cast<const void*>(&pair_kernel<8, 9, 3, 1024>),
                hipFuncAttributeMaxDynamicSharedMemorySize, N_L3 * 4);
            attr_done = 1;
        }

        const int n4 = 16 * 524288 * 2 / 4;
        convert_kernel<<<(n4 + 255) / 256, 256, 0, stream>>>(
            (const vf4*)emb, (vh4*)tb, n4);
        remap_kernel<<<dim3((N_L3 + 255) / 256, 4), 256, 0, stream>>>(
            (const vf2*)emb, dense);

        const int g1024 = (half + 1023) / 1024;
        const int g256  = (half + 255) / 256;
        pair_kernel<4, 5, 1, 1024><<<g1024, 1024, (N_L0 + N_L1) * 4, stream>>>(
            x, tb, dn, ws, B, half);
        pair_kernel<6, 7, 2, 1024><<<g1024, 1024, N_L2 * 4, stream>>>(
            x, tb, dn, ws, B, half);
        pair_kernel<8, 9, 3, 1024><<<g1024, 1024, N_L3 * 4, stream>>>(
            x, tb, dn, ws, B, half);
        pair_kernel<10, 11, 0, 256><<<g256, 256, 0, stream>>>(
            x, tb, dn, ws, B, half);
        pair_kernel<12, 13, 0, 256><<<g256, 256, 0, stream>>>(
            x, tb, dn, ws, B, half);
        pair_kernel<14, 15, 0, 256><<<g256, 256, 0, stream>>>(
            x, tb, dn, ws, B, half);

        transpose_kernel<<<(B + 255) / 256, 256, 0, stream>>>(ws, (vf4*)d_out, B);
    } else {
        const int grid = (half + 255) / 256;
        monolith_kernel<<<grid, 256, 0, stream>>>(
            x, (const vf2*)emb, (vf4*)d_out, B, half);
    }
}